// Round 9
// baseline (285.887 us; speedup 1.0000x reference)
//
#include <hip/hip_runtime.h>

#define B_ 4
#define C_ 256
#define N_ 4096
#define D_ 64

typedef __bf16 bf16x8 __attribute__((ext_vector_type(8)));
typedef float floatx4 __attribute__((ext_vector_type(4)));
typedef unsigned short ushort8v __attribute__((ext_vector_type(8)));
typedef unsigned short ushort4v __attribute__((ext_vector_type(4)));

static __device__ __forceinline__ unsigned short f2bf(float f) {
    unsigned int u = __builtin_bit_cast(unsigned int, f);
    u += 0x7fffu + ((u >> 16) & 1u);   // RNE
    return (unsigned short)(u >> 16);
}
static __device__ __forceinline__ float bf2f(unsigned short h) {
    unsigned int u = ((unsigned int)h) << 16;
    return __builtin_bit_cast(float, u);
}

// async global->LDS DMA, 16B/lane, dst = wave-uniform base + lane*16
#define GLOAD16(gp, lp)                                                      \
    __builtin_amdgcn_global_load_lds(                                        \
        (const __attribute__((address_space(1))) void*)(gp),                 \
        (__attribute__((address_space(3))) void*)(lp), 16, 0, 0)

// ---------------------------------------------------------------------------
// Fused MFMA projection (identical to R7, + zeroes the split-K tickets).
// ---------------------------------------------------------------------------
__global__ __launch_bounds__(256, 3) void proj_kernel(
    const float* __restrict__ x,
    const float* __restrict__ Wq, const float* __restrict__ bq,
    const float* __restrict__ Wk, const float* __restrict__ bk,
    const float* __restrict__ Wv, const float* __restrict__ bv,
    unsigned short* __restrict__ Qg, unsigned short* __restrict__ Kg,
    unsigned short* __restrict__ Vg, unsigned int* __restrict__ Tick)
{
    __shared__ __align__(16) unsigned short smem[64 * 264];  // 33792 B
    unsigned short* xs = smem;          // x tile, swizzled [n][264]
    unsigned short* Lt = smem;          // epilogue tile [128][72] (union)

    const int n0 = blockIdx.x * 64;
    const int f0 = blockIdx.y * 128;
    const int b  = blockIdx.z;
    const int t  = threadIdx.x;
    const int w  = t >> 6;
    const int lane = t & 63;
    const int g  = lane >> 4;
    const int m  = lane & 15;

    if (blockIdx.y == 0 && t == 0) Tick[b * 64 + blockIdx.x] = 0;

    // ---- stage x tile -> LDS bf16, swizzled
#pragma unroll
    for (int k = 0; k < 16; ++k) {
        int e  = t + 256 * k;
        int c  = e >> 4;
        int n4 = (e & 15) * 4;
        float4 v = *(const float4*)(x + ((size_t)b*C_ + c)*N_ + n0 + n4);
        float vv[4] = {v.x, v.y, v.z, v.w};
#pragma unroll
        for (int j = 0; j < 4; ++j) {
            int n = n4 + j;
            xs[n*264 + (((c >> 3) ^ (n & 7)) << 3) + (c & 7)] = f2bf(vv[j]);
        }
    }

    float bias_[2][4];
    const float* wbase[2];
#pragma unroll
    for (int mt = 0; mt < 2; ++mt) {
#pragma unroll
        for (int r = 0; r < 4; ++r) {
            int fg = f0 + 32*w + 16*mt + 4*g + r;
            bias_[mt][r] = (fg < 64) ? bq[fg]
                         : (fg < 128) ? bk[fg - 64] : bv[fg - 128];
        }
        int f = f0 + 32*w + 16*mt + m;
        wbase[mt] = (f < 64)  ? (Wq + (size_t)f * C_)
                  : (f < 128) ? (Wk + (size_t)(f - 64) * C_)
                              : (Wv + (size_t)(f - 128) * C_);
    }

    floatx4 acc[2][4];
#pragma unroll
    for (int mt = 0; mt < 2; ++mt)
#pragma unroll
        for (int nt = 0; nt < 4; ++nt) acc[mt][nt] = (floatx4){0.f,0.f,0.f,0.f};

    __syncthreads();   // x tile staged

#pragma unroll
    for (int ks = 0; ks < 8; ++ks) {
        bf16x8 af[2];
#pragma unroll
        for (int mt = 0; mt < 2; ++mt) {
            float4 wa = *(const float4*)(wbase[mt] + 32*ks + 8*g);
            float4 wb = *(const float4*)(wbase[mt] + 32*ks + 8*g + 4);
            ushort8v u;
            u[0]=f2bf(wa.x); u[1]=f2bf(wa.y); u[2]=f2bf(wa.z); u[3]=f2bf(wa.w);
            u[4]=f2bf(wb.x); u[5]=f2bf(wb.y); u[6]=f2bf(wb.z); u[7]=f2bf(wb.w);
            af[mt] = __builtin_bit_cast(bf16x8, u);
        }
#pragma unroll
        for (int nt = 0; nt < 4; ++nt) {
            int n = 16*nt + m;
            bf16x8 bfr = *(const bf16x8*)
                &xs[n*264 + (((4*ks + g) ^ (n & 7)) << 3)];
#pragma unroll
            for (int mt = 0; mt < 2; ++mt)
                acc[mt][nt] = __builtin_amdgcn_mfma_f32_16x16x32_bf16(
                                  af[mt], bfr, acc[mt][nt], 0, 0, 0);
        }
    }

    __syncthreads();   // xs dead -> Lt overlay

#pragma unroll
    for (int mt = 0; mt < 2; ++mt)
#pragma unroll
        for (int nt = 0; nt < 4; ++nt)
#pragma unroll
            for (int r = 0; r < 4; ++r)
                Lt[(32*w + 16*mt + 4*g + r)*72 + 16*nt + m] =
                    f2bf(acc[mt][nt][r] + bias_[mt][r]);
    __syncthreads();

    if (f0 == 0) {
#pragma unroll
        for (int k = 0; k < 4; ++k) {
            int e   = t + 256 * k;
            int fq0 = (e >> 6) * 8;
            int nl  = e & 63;
            ushort8v u;
#pragma unroll
            for (int j = 0; j < 8; ++j) u[j] = Lt[(fq0 + j)*72 + nl];
            unsigned short* dst = (fq0 < 64)
                ? (Qg + ((size_t)b*N_ + n0 + nl)*D_ + fq0)
                : (Kg + ((size_t)b*N_ + n0 + nl)*D_ + (fq0 - 64));
            *(ushort8v*)dst = u;
        }
    } else {
        const int cb = f0 - 128;
#pragma unroll
        for (int k = 0; k < 4; ++k) {
            int e  = t + 256 * k;
            int fr = e >> 3;
            int n8 = (e & 7) * 8;
            ushort8v u = *(const ushort8v*)&Lt[fr*72 + n8];
            *(ushort8v*)(Vg + ((size_t)b*C_ + cb + fr)*N_ + n0 + n8) = u;
        }
    }
}

// ---------------------------------------------------------------------------
// MFMA flash attention, split-K 2, XCD-pinned (R7), with FUSED COMBINE:
// after storing partials, each block increments a per-(b,tile) ticket;
// the SECOND finisher (device-scope fences per G16) normalizes both halves
// and writes the final output for the whole tile (256 ch x 64 n), fused
// with gamma*O/L + x. Deletes the combine dispatch; its HBM traffic
// overlaps still-running flash blocks.
// ---------------------------------------------------------------------------
__global__ __launch_bounds__(256, 2) void flash_kernel(
    const unsigned short* __restrict__ Qg, const unsigned short* __restrict__ Kg,
    const unsigned short* __restrict__ Vg,
    unsigned short* __restrict__ Op, float* __restrict__ ML,
    unsigned int* __restrict__ Tick,
    const float* __restrict__ x, const float* __restrict__ gamma,
    float* __restrict__ out)
{
    __shared__ __align__(16) unsigned short Vlds[32 * 512];    // 32 KB
    __shared__ __align__(16) unsigned short Klds[2][8 * 512];  // 16 KB
    __shared__ __align__(16) unsigned short PA[8 * 64 * 8];    //  8 KB
    __shared__ float AL[64];
    __shared__ int doneFlag;

    const int g8   = blockIdx.x;        // half + 2*b  (XCD pin)
    const int tile = blockIdx.y;
    const int half = g8 & 1;
    const int b    = g8 >> 1;
    const int n0   = tile * 64;
    const int t    = threadIdx.x;
    const int w    = t >> 6;
    const int lane = t & 63;
    const int g    = lane >> 4;
    const int m    = lane & 15;

    const unsigned short* Qb = Qg + ((size_t)b*N_ + n0)*D_;
    const unsigned short* Kb = Kg + (size_t)b*N_*D_;
    const unsigned short* Vb = Vg + (size_t)b*C_*N_;

    const int cstart = half * 32;
    const int cend   = cstart + 32;

    bf16x8 qf[2];
#pragma unroll
    for (int ks = 0; ks < 2; ++ks)
        qf[ks] = *(const bf16x8*)(Qb + (size_t)(16*w + m)*D_ + 32*ks + 8*g);

    floatx4 accO[4][4];
#pragma unroll
    for (int rt = 0; rt < 4; ++rt)
#pragma unroll
        for (int ct = 0; ct < 4; ++ct)
            accO[rt][ct] = (floatx4){0.f, 0.f, 0.f, 0.f};

    float mrow = -1e30f, lrow = 0.f;

    // prologue: DMA K(cstart) into Klds[0]
#pragma unroll
    for (int u = 0; u < 2; ++u) {
        const unsigned short* gp =
            Kb + (size_t)(cstart*64 + 16*w + m)*D_ + 32*u + 8*g;
        GLOAD16(gp, &Klds[0][(2*w + u) * 512]);
    }
    __syncthreads();

    for (int t64 = cstart; t64 < cend; ++t64) {
        const int j0 = t64 * 64;
        const int kb = (t64 - cstart) & 1;

        // DMA V(t64)
#pragma unroll
        for (int u = 0; u < 8; ++u) {
            int sidx = 8*w + u;
            int ks   = sidx >> 4;
            int cb   = sidx & 15;
            const unsigned short* gp =
                Vb + (size_t)(16*cb + m)*N_ + j0 + 32*ks + 8*g;
            GLOAD16(gp, &Vlds[sidx * 512]);
        }
        // DMA K(t64+1) into other buffer
        if (t64 + 1 < cend) {
#pragma unroll
            for (int u = 0; u < 2; ++u) {
                const unsigned short* gp =
                    Kb + (size_t)((t64+1)*64 + 16*w + m)*D_ + 32*u + 8*g;
                GLOAD16(gp, &Klds[kb ^ 1][(2*w + u) * 512]);
            }
        }

        // S^T = K*Q from Klds[kb]
        floatx4 accST[4];
#pragma unroll
        for (int jt = 0; jt < 4; ++jt) accST[jt] = (floatx4){0.f,0.f,0.f,0.f};
#pragma unroll
        for (int ks = 0; ks < 2; ++ks)
#pragma unroll
            for (int jt = 0; jt < 4; ++jt) {
                bf16x8 kfr = *(const bf16x8*)
                    &Klds[kb][(jt*2 + ks)*512 + lane*8];
                accST[jt] = __builtin_amdgcn_mfma_f32_16x16x32_bf16(
                                kfr, qf[ks], accST[jt], 0, 0, 0);
            }

        // online softmax: in-register over 16 keys/lane + 2 shfls
        float mx = -1e30f;
#pragma unroll
        for (int jt = 0; jt < 4; ++jt)
#pragma unroll
            for (int r = 0; r < 4; ++r) mx = fmaxf(mx, accST[jt][r]);
        mx = fmaxf(mx, __shfl_xor(mx, 16));
        mx = fmaxf(mx, __shfl_xor(mx, 32));
        float mnew  = fmaxf(mrow, mx);
        float alpha = __expf(mrow - mnew);
        mrow = mnew;
        float p[4][4];
        float rs = 0.f;
#pragma unroll
        for (int jt = 0; jt < 4; ++jt)
#pragma unroll
            for (int r = 0; r < 4; ++r) {
                float e = __expf(accST[jt][r] - mnew);
                p[jt][r] = e;
                rs += e;
            }
        rs += __shfl_xor(rs, 16);
        rs += __shfl_xor(rs, 32);
        lrow = lrow * alpha + rs;

        if (g == 0) AL[16*w + m] = alpha;

        // P -> LDS, direct b64 stores into A-frag layout
#pragma unroll
        for (int jt = 0; jt < 4; ++jt) {
            ushort4v u;
#pragma unroll
            for (int r = 0; r < 4; ++r) u[r] = f2bf(p[jt][r]);
            int frag = (w*2 + (jt >> 1))*64 + 16*(2*(jt & 1) + (g >> 1)) + m;
            *(ushort4v*)&PA[frag*8 + 4*(g & 1)] = u;
        }

        __syncthreads();   // barrier A: drains V DMA (+K prefetch)

        // PV: O = alpha*O + P V
#pragma unroll
        for (int rt = 0; rt < 4; ++rt) {
            floatx4 a4 = *(const floatx4*)&AL[16*rt + 4*g];
#pragma unroll
            for (int ct = 0; ct < 4; ++ct)
                accO[rt][ct] *= a4;
        }
#pragma unroll
        for (int ks = 0; ks < 2; ++ks) {
            bf16x8 pf[4];
#pragma unroll
            for (int rt = 0; rt < 4; ++rt)
                pf[rt] = *(const bf16x8*)&PA[((rt*2 + ks)*64 + lane)*8];
#pragma unroll
            for (int ct = 0; ct < 4; ++ct) {
                int sidx = ks*16 + 4*w + ct;
                bf16x8 vfrag = *(const bf16x8*)&Vlds[sidx*512 + lane*8];
#pragma unroll
                for (int rt = 0; rt < 4; ++rt)
                    accO[rt][ct] = __builtin_amdgcn_mfma_f32_16x16x32_bf16(
                                       pf[rt], vfrag, accO[rt][ct], 0, 0, 0);
            }
        }

        __syncthreads();   // barrier B
    }

    // ---- store unnormalized partial O (bf16) and per-query m,l ----
    const size_t tbase = ((size_t)(half*B_ + b)*64 + tile);
    unsigned short* Ob = Op + tbase * (C_ * 64);
    float* ml = ML + tbase * 128;

    if (g == 0) {
        ml[16*w + m]      = mrow;
        ml[64 + 16*w + m] = lrow;
    }

#pragma unroll
    for (int rt = 0; rt < 4; ++rt)
#pragma unroll
        for (int ct = 0; ct < 4; ++ct) {
            int c = 64*w + 16*ct + m;
            ushort4v u4;
#pragma unroll
            for (int r = 0; r < 4; ++r) u4[r] = f2bf(accO[rt][ct][r]);
            *(ushort4v*)(Ob + (size_t)c*64 + 16*rt + 4*g) = u4;
        }

    // ---- split-K ticket: second finisher combines this (b,tile) ----
    __threadfence();     // release: partials visible device-wide
    __syncthreads();     // all threads' stores done
    if (t == 0) {
        unsigned int old = atomicAdd(&Tick[b*64 + tile], 1u);
        doneFlag = (old == 1);
    }
    __syncthreads();
    if (!doneFlag) return;

    __threadfence();     // acquire: partner's partials

    // ---- combine: out = gamma*(w0*O0 + w1*O1) + x, full tile ----
    float* sc0 = (float*)Vlds;
    float* sc1 = sc0 + 64;
    if (t < 64) {
        const float* ml0 = ML + ((size_t)(0*B_ + b)*64 + tile)*128;
        const float* ml1 = ML + ((size_t)(1*B_ + b)*64 + tile)*128;
        float m0 = ml0[t], l0 = ml0[64 + t];
        float m1 = ml1[t], l1 = ml1[64 + t];
        float M  = fmaxf(m0, m1);
        float f0 = __expf(m0 - M), f1 = __expf(m1 - M);
        float L  = f0*l0 + f1*l1;
        float gm = gamma[0];
        sc0[t] = gm * f0 / L;
        sc1[t] = gm * f1 / L;
    }
    __syncthreads();

    const int nq = t & 15;
    const float* xb = x   + (size_t)b*C_*N_;
    float*       ob = out + (size_t)b*C_*N_;
    const unsigned short* O0 = Op + ((size_t)(0*B_ + b)*64 + tile)*(C_*64);
    const unsigned short* O1 = Op + ((size_t)(1*B_ + b)*64 + tile)*(C_*64);

    float s0[4], s1[4];
#pragma unroll
    for (int k = 0; k < 4; ++k) { s0[k] = sc0[4*nq + k]; s1[k] = sc1[4*nq + k]; }

#pragma unroll 4
    for (int i = 0; i < 16; ++i) {
        int c = 16*i + (t >> 4);
        float4 x4 = *(const float4*)(xb + (size_t)c*N_ + n0 + 4*nq);
        ushort4v a4 = *(const ushort4v*)(O0 + (size_t)c*64 + 4*nq);
        ushort4v b4 = *(const ushort4v*)(O1 + (size_t)c*64 + 4*nq);
        float4 y;
        y.x = s0[0]*bf2f(a4[0]) + s1[0]*bf2f(b4[0]) + x4.x;
        y.y = s0[1]*bf2f(a4[1]) + s1[1]*bf2f(b4[1]) + x4.y;
        y.z = s0[2]*bf2f(a4[2]) + s1[2]*bf2f(b4[2]) + x4.z;
        y.w = s0[3]*bf2f(a4[3]) + s1[3]*bf2f(b4[3]) + x4.w;
        *(float4*)(ob + (size_t)c*N_ + n0 + 4*nq) = y;
    }
}

// ---------------------------------------------------------------------------
extern "C" void kernel_launch(void* const* d_in, const int* in_sizes, int n_in,
                              void* d_out, int out_size, void* d_ws, size_t ws_size,
                              hipStream_t stream) {
    const float* x     = (const float*)d_in[0];
    const float* Wq    = (const float*)d_in[1];
    const float* bq    = (const float*)d_in[2];
    const float* Wk    = (const float*)d_in[3];
    const float* bk    = (const float*)d_in[4];
    const float* Wv    = (const float*)d_in[5];
    const float* bv    = (const float*)d_in[6];
    const float* gamma = (const float*)d_in[7];
    float* out = (float*)d_out;

    // ws layout (~29 MB):
    unsigned short* Qg = (unsigned short*)d_ws;            // 2 MiB
    unsigned short* Kg = Qg + (size_t)B_*N_*D_;            // 2 MiB
    unsigned short* Vg = Kg + (size_t)B_*N_*D_;            // 8 MiB
    unsigned short* Op = Vg + (size_t)B_*C_*N_;            // 16.8 MiB
    float* ML = (float*)(Op + (size_t)2*B_*64*C_*64);      // 256 KiB
    unsigned int* Tick = (unsigned int*)(ML + (size_t)2*B_*64*128); // 1 KiB

    proj_kernel<<<dim3(64, 3, 4), 256, 0, stream>>>(x, Wq, bq, Wk, bk, Wv, bv,
                                                    Qg, Kg, Vg, Tick);
    flash_kernel<<<dim3(8, 64), 256, 0, stream>>>(Qg, Kg, Vg, Op, ML, Tick,
                                                  x, gamma, out);
}

// Round 10
// 177.641 us; speedup vs baseline: 1.6094x; 1.6094x over previous
//
#include <hip/hip_runtime.h>

#define B_ 4
#define C_ 256
#define N_ 4096
#define D_ 64

typedef __bf16 bf16x8 __attribute__((ext_vector_type(8)));
typedef float floatx4 __attribute__((ext_vector_type(4)));
typedef unsigned short ushort8v __attribute__((ext_vector_type(8)));
typedef unsigned short ushort4v __attribute__((ext_vector_type(4)));
typedef unsigned short ushort2v __attribute__((ext_vector_type(2)));

static __device__ __forceinline__ unsigned short f2bf(float f) {
    unsigned int u = __builtin_bit_cast(unsigned int, f);
    u += 0x7fffu + ((u >> 16) & 1u);   // RNE
    return (unsigned short)(u >> 16);
}
static __device__ __forceinline__ float bf2f(unsigned short h) {
    unsigned int u = ((unsigned int)h) << 16;
    return __builtin_bit_cast(float, u);
}

// async global->LDS DMA, 16B/lane, dst = wave-uniform base + lane*16
#define GLOAD16(gp, lp)                                                      \
    __builtin_amdgcn_global_load_lds(                                        \
        (const __attribute__((address_space(1))) void*)(gp),                 \
        (__attribute__((address_space(3))) void*)(lp), 16, 0, 0)

// ---------------------------------------------------------------------------
// One-time W conversion into A-frag-native layout:
//   WbfA[((ft*8 + ks)*64 + lane)*8 + j] = W[16*ft + (lane&15)]
//                                          [32*ks + 8*(lane>>4) + j]
// so proj's A-frag load is wave-uniform base + lane*16B (coalesced 1 KB).
// 384 f-rows -> ft 0..23, 98304 shorts total (192 KiB).
// ---------------------------------------------------------------------------
__global__ __launch_bounds__(256) void convert_w(
    const float* __restrict__ Wq, const float* __restrict__ Wk,
    const float* __restrict__ Wv, unsigned short* __restrict__ WbfA)
{
    int tid = blockIdx.x * 256 + threadIdx.x;   // 0..24575
    int p0  = tid * 4;                          // output short index
    int j0   = p0 & 7;
    int lane = (p0 >> 3) & 63;
    int sidx = p0 >> 9;
    int ft = sidx >> 3, ks = sidx & 7;
    int m  = lane & 15, g = lane >> 4;
    int f  = 16*ft + m;
    int c  = 32*ks + 8*g + j0;
    const float* src = (f < 64)  ? (Wq + (size_t)f * C_)
                     : (f < 128) ? (Wk + (size_t)(f - 64) * C_)
                                 : (Wv + (size_t)(f - 128) * C_);
    float4 v = *(const float4*)(src + c);
    ushort4v u;
    u[0] = f2bf(v.x); u[1] = f2bf(v.y); u[2] = f2bf(v.z); u[3] = f2bf(v.w);
    *(ushort4v*)(WbfA + p0) = u;
}

// ---------------------------------------------------------------------------
// MFMA projection. A-frags: coalesced bf16 loads from WbfA (pre-converted,
// L2-hot). B-frags: x tile staged fp32->bf16 into XOR-swizzled LDS
// (pair-packed b32 writes). Epilogue via LDS overlay, coalesced stores.
// ---------------------------------------------------------------------------
__global__ __launch_bounds__(256, 3) void proj_kernel(
    const float* __restrict__ x, const unsigned short* __restrict__ WbfA,
    const float* __restrict__ bq, const float* __restrict__ bk,
    const float* __restrict__ bv,
    unsigned short* __restrict__ Qg, unsigned short* __restrict__ Kg,
    unsigned short* __restrict__ Vg)
{
    __shared__ __align__(16) unsigned short smem[64 * 264];  // 33792 B
    unsigned short* xs = smem;          // x tile, swizzled [n][264]
    unsigned short* Lt = smem;          // epilogue tile [128][72] (union)

    const int n0 = blockIdx.x * 64;
    const int f0 = blockIdx.y * 128;
    const int b  = blockIdx.z;
    const int t  = threadIdx.x;
    const int w  = t >> 6;
    const int lane = t & 63;
    const int g  = lane >> 4;
    const int m  = lane & 15;

    // ---- stage x tile -> LDS bf16, swizzled; c-pair packed b32 writes ----
#pragma unroll
    for (int k = 0; k < 8; ++k) {
        int e  = t + 256 * k;           // 0..2047
        int cp = e >> 4;                // 0..127
        int c  = 2 * cp;
        int n4 = (e & 15) * 4;
        float4 v0 = *(const float4*)(x + ((size_t)b*C_ + c    )*N_ + n0 + n4);
        float4 v1 = *(const float4*)(x + ((size_t)b*C_ + c + 1)*N_ + n0 + n4);
        float a0[4] = {v0.x, v0.y, v0.z, v0.w};
        float a1[4] = {v1.x, v1.y, v1.z, v1.w};
#pragma unroll
        for (int j = 0; j < 4; ++j) {
            int n = n4 + j;
            ushort2v u2;
            u2[0] = f2bf(a0[j]);
            u2[1] = f2bf(a1[j]);
            *(ushort2v*)&xs[n*264 + (((c >> 3) ^ (n & 7)) << 3) + (c & 7)] = u2;
        }
    }

    float bias_[2][4];
#pragma unroll
    for (int mt = 0; mt < 2; ++mt)
#pragma unroll
        for (int r = 0; r < 4; ++r) {
            int fg = f0 + 32*w + 16*mt + 4*g + r;
            bias_[mt][r] = (fg < 64) ? bq[fg]
                         : (fg < 128) ? bk[fg - 64] : bv[fg - 128];
        }

    // A-frag segment bases: seg = (f0/16 + 2w + mt)*8 + ks
    const unsigned short* Wa0 = WbfA + (size_t)(((f0 >> 4) + 2*w    )*8)*512
                              + lane*8;
    const unsigned short* Wa1 = WbfA + (size_t)(((f0 >> 4) + 2*w + 1)*8)*512
                              + lane*8;

    floatx4 acc[2][4];
#pragma unroll
    for (int mt = 0; mt < 2; ++mt)
#pragma unroll
        for (int nt = 0; nt < 4; ++nt) acc[mt][nt] = (floatx4){0.f,0.f,0.f,0.f};

    __syncthreads();   // x tile staged

#pragma unroll
    for (int ks = 0; ks < 8; ++ks) {
        bf16x8 af[2];
        af[0] = *(const bf16x8*)(Wa0 + ks*512);
        af[1] = *(const bf16x8*)(Wa1 + ks*512);
#pragma unroll
        for (int nt = 0; nt < 4; ++nt) {
            int n = 16*nt + m;
            bf16x8 bfr = *(const bf16x8*)
                &xs[n*264 + (((4*ks + g) ^ (n & 7)) << 3)];
#pragma unroll
            for (int mt = 0; mt < 2; ++mt)
                acc[mt][nt] = __builtin_amdgcn_mfma_f32_16x16x32_bf16(
                                  af[mt], bfr, acc[mt][nt], 0, 0, 0);
        }
    }

    __syncthreads();   // xs dead -> Lt overlay

#pragma unroll
    for (int mt = 0; mt < 2; ++mt)
#pragma unroll
        for (int nt = 0; nt < 4; ++nt)
#pragma unroll
            for (int r = 0; r < 4; ++r)
                Lt[(32*w + 16*mt + 4*g + r)*72 + 16*nt + m] =
                    f2bf(acc[mt][nt][r] + bias_[mt][r]);
    __syncthreads();

    if (f0 == 0) {
#pragma unroll
        for (int k = 0; k < 4; ++k) {
            int e   = t + 256 * k;
            int fq0 = (e >> 6) * 8;
            int nl  = e & 63;
            ushort8v u;
#pragma unroll
            for (int j = 0; j < 8; ++j) u[j] = Lt[(fq0 + j)*72 + nl];
            unsigned short* dst = (fq0 < 64)
                ? (Qg + ((size_t)b*N_ + n0 + nl)*D_ + fq0)
                : (Kg + ((size_t)b*N_ + n0 + nl)*D_ + (fq0 - 64));
            *(ushort8v*)dst = u;
        }
    } else {
        const int cb = f0 - 128;
#pragma unroll
        for (int k = 0; k < 4; ++k) {
            int e  = t + 256 * k;
            int fr = e >> 3;
            int n8 = (e & 7) * 8;
            ushort8v u = *(const ushort8v*)&Lt[fr*72 + n8];
            *(ushort8v*)(Vg + ((size_t)b*C_ + cb + fr)*N_ + n0 + n8) = u;
        }
    }
}

// ---------------------------------------------------------------------------
// MFMA flash attention (R7 verbatim — 88.3 us measured): split-K 2,
// XCD-pinned grid (id%8 = half+2b), K+V staged via global_load_lds.
// ---------------------------------------------------------------------------
__global__ __launch_bounds__(256, 2) void flash_kernel(
    const unsigned short* __restrict__ Qg, const unsigned short* __restrict__ Kg,
    const unsigned short* __restrict__ Vg,
    unsigned short* __restrict__ Opart, float* __restrict__ ML)
{
    __shared__ __align__(16) unsigned short Vlds[32 * 512];    // 32 KB
    __shared__ __align__(16) unsigned short Klds[2][8 * 512];  // 16 KB
    __shared__ __align__(16) unsigned short PA[8 * 64 * 8];    //  8 KB
    __shared__ float AL[64];

    const int g8   = blockIdx.x;        // half + 2*b  (XCD pin)
    const int tile = blockIdx.y;
    const int half = g8 & 1;
    const int b    = g8 >> 1;
    const int n0   = tile * 64;
    const int t    = threadIdx.x;
    const int w    = t >> 6;
    const int lane = t & 63;
    const int g    = lane >> 4;
    const int m    = lane & 15;

    const unsigned short* Qb = Qg + ((size_t)b*N_ + n0)*D_;
    const unsigned short* Kb = Kg + (size_t)b*N_*D_;
    const unsigned short* Vb = Vg + (size_t)b*C_*N_;

    const int cstart = half * 32;
    const int cend   = cstart + 32;

    bf16x8 qf[2];
#pragma unroll
    for (int ks = 0; ks < 2; ++ks)
        qf[ks] = *(const bf16x8*)(Qb + (size_t)(16*w + m)*D_ + 32*ks + 8*g);

    floatx4 accO[4][4];
#pragma unroll
    for (int rt = 0; rt < 4; ++rt)
#pragma unroll
        for (int ct = 0; ct < 4; ++ct)
            accO[rt][ct] = (floatx4){0.f, 0.f, 0.f, 0.f};

    float mrow = -1e30f, lrow = 0.f;

    // prologue: DMA K(cstart) into Klds[0]
#pragma unroll
    for (int u = 0; u < 2; ++u) {
        const unsigned short* gp =
            Kb + (size_t)(cstart*64 + 16*w + m)*D_ + 32*u + 8*g;
        GLOAD16(gp, &Klds[0][(2*w + u) * 512]);
    }
    __syncthreads();

    for (int t64 = cstart; t64 < cend; ++t64) {
        const int j0 = t64 * 64;
        const int kb = (t64 - cstart) & 1;

        // DMA V(t64)
#pragma unroll
        for (int u = 0; u < 8; ++u) {
            int sidx = 8*w + u;
            int ks   = sidx >> 4;
            int cb   = sidx & 15;
            const unsigned short* gp =
                Vb + (size_t)(16*cb + m)*N_ + j0 + 32*ks + 8*g;
            GLOAD16(gp, &Vlds[sidx * 512]);
        }
        // DMA K(t64+1) into other buffer
        if (t64 + 1 < cend) {
#pragma unroll
            for (int u = 0; u < 2; ++u) {
                const unsigned short* gp =
                    Kb + (size_t)((t64+1)*64 + 16*w + m)*D_ + 32*u + 8*g;
                GLOAD16(gp, &Klds[kb ^ 1][(2*w + u) * 512]);
            }
        }

        // S^T = K*Q from Klds[kb]
        floatx4 accST[4];
#pragma unroll
        for (int jt = 0; jt < 4; ++jt) accST[jt] = (floatx4){0.f,0.f,0.f,0.f};
#pragma unroll
        for (int ks = 0; ks < 2; ++ks)
#pragma unroll
            for (int jt = 0; jt < 4; ++jt) {
                bf16x8 kfr = *(const bf16x8*)
                    &Klds[kb][(jt*2 + ks)*512 + lane*8];
                accST[jt] = __builtin_amdgcn_mfma_f32_16x16x32_bf16(
                                kfr, qf[ks], accST[jt], 0, 0, 0);
            }

        // online softmax: in-register over 16 keys/lane + 2 shfls
        float mx = -1e30f;
#pragma unroll
        for (int jt = 0; jt < 4; ++jt)
#pragma unroll
            for (int r = 0; r < 4; ++r) mx = fmaxf(mx, accST[jt][r]);
        mx = fmaxf(mx, __shfl_xor(mx, 16));
        mx = fmaxf(mx, __shfl_xor(mx, 32));
        float mnew  = fmaxf(mrow, mx);
        float alpha = __expf(mrow - mnew);
        mrow = mnew;
        float p[4][4];
        float rs = 0.f;
#pragma unroll
        for (int jt = 0; jt < 4; ++jt)
#pragma unroll
            for (int r = 0; r < 4; ++r) {
                float e = __expf(accST[jt][r] - mnew);
                p[jt][r] = e;
                rs += e;
            }
        rs += __shfl_xor(rs, 16);
        rs += __shfl_xor(rs, 32);
        lrow = lrow * alpha + rs;

        if (g == 0) AL[16*w + m] = alpha;

        // P -> LDS, direct b64 stores into A-frag layout
#pragma unroll
        for (int jt = 0; jt < 4; ++jt) {
            ushort4v u;
#pragma unroll
            for (int r = 0; r < 4; ++r) u[r] = f2bf(p[jt][r]);
            int frag = (w*2 + (jt >> 1))*64 + 16*(2*(jt & 1) + (g >> 1)) + m;
            *(ushort4v*)&PA[frag*8 + 4*(g & 1)] = u;
        }

        __syncthreads();   // barrier A: drains V DMA (+K prefetch)

        // PV: O = alpha*O + P V
#pragma unroll
        for (int rt = 0; rt < 4; ++rt) {
            floatx4 a4 = *(const floatx4*)&AL[16*rt + 4*g];
#pragma unroll
            for (int ct = 0; ct < 4; ++ct)
                accO[rt][ct] *= a4;
        }
#pragma unroll
        for (int ks = 0; ks < 2; ++ks) {
            bf16x8 pf[4];
#pragma unroll
            for (int rt = 0; rt < 4; ++rt)
                pf[rt] = *(const bf16x8*)&PA[((rt*2 + ks)*64 + lane)*8];
#pragma unroll
            for (int ct = 0; ct < 4; ++ct) {
                int sidx = ks*16 + 4*w + ct;
                bf16x8 vfrag = *(const bf16x8*)&Vlds[sidx*512 + lane*8];
#pragma unroll
                for (int rt = 0; rt < 4; ++rt)
                    accO[rt][ct] = __builtin_amdgcn_mfma_f32_16x16x32_bf16(
                                       pf[rt], vfrag, accO[rt][ct], 0, 0, 0);
            }
        }

        __syncthreads();   // barrier B
    }

    // store unnormalized partial O (bf16) and per-query m,l
    const size_t tbase = ((size_t)(half*B_ + b)*64 + tile);
    unsigned short* Ob = Opart + tbase * (C_ * 64);
    float* ml = ML + tbase * 128;

    if (g == 0) {
        ml[16*w + m]      = mrow;
        ml[64 + 16*w + m] = lrow;
    }

#pragma unroll
    for (int rt = 0; rt < 4; ++rt)
#pragma unroll
        for (int ct = 0; ct < 4; ++ct) {
            int c = 64*w + 16*ct + m;
            ushort4v u4;
#pragma unroll
            for (int r = 0; r < 4; ++r) u4[r] = f2bf(accO[rt][ct][r]);
            *(ushort4v*)(Ob + (size_t)c*64 + 16*rt + 4*g) = u4;
        }
}

// ---------------------------------------------------------------------------
// Combine (R7 verbatim): S=2 static, c-split across 2 blocks.
// ---------------------------------------------------------------------------
__global__ __launch_bounds__(256) void combine_kernel(
    const unsigned short* __restrict__ Opart, const float* __restrict__ ML,
    const float* __restrict__ x, const float* __restrict__ gamma,
    float* __restrict__ out)
{
    __shared__ float sc0[64], sc1[64];
    const int tile  = blockIdx.x;
    const int chalf = blockIdx.y;
    const int b     = blockIdx.z;
    const int n0    = tile * 64;
    const int t     = threadIdx.x;

    if (t < 64) {
        const float* ml0 = ML + ((size_t)(0*B_ + b)*64 + tile)*128;
        const float* ml1 = ML + ((size_t)(1*B_ + b)*64 + tile)*128;
        float m0 = ml0[t], l0 = ml0[64 + t];
        float m1 = ml1[t], l1 = ml1[64 + t];
        float M  = fmaxf(m0, m1);
        float f0 = __expf(m0 - M), f1 = __expf(m1 - M);
        float L  = f0*l0 + f1*l1;
        float gm = gamma[0];
        sc0[t] = gm * f0 / L;
        sc1[t] = gm * f1 / L;
    }
    __syncthreads();

    const int nq = t & 15;
    const float* xb = x   + (size_t)b*C_*N_;
    float*       ob = out + (size_t)b*C_*N_;
    const unsigned short* O0 = Opart + ((size_t)(0*B_ + b)*64 + tile)*(C_*64);
    const unsigned short* O1 = Opart + ((size_t)(1*B_ + b)*64 + tile)*(C_*64);

    float s0[4], s1[4];
#pragma unroll
    for (int k = 0; k < 4; ++k) { s0[k] = sc0[4*nq + k]; s1[k] = sc1[4*nq + k]; }

#pragma unroll 4
    for (int i = 0; i < 8; ++i) {
        int c = 128*chalf + 16*i + (t >> 4);
        float4 x4 = *(const float4*)(xb + (size_t)c*N_ + n0 + 4*nq);
        ushort4v a4 = *(const ushort4v*)(O0 + (size_t)c*64 + 4*nq);
        ushort4v b4 = *(const ushort4v*)(O1 + (size_t)c*64 + 4*nq);
        float4 y;
        y.x = s0[0]*bf2f(a4[0]) + s1[0]*bf2f(b4[0]) + x4.x;
        y.y = s0[1]*bf2f(a4[1]) + s1[1]*bf2f(b4[1]) + x4.y;
        y.z = s0[2]*bf2f(a4[2]) + s1[2]*bf2f(b4[2]) + x4.z;
        y.w = s0[3]*bf2f(a4[3]) + s1[3]*bf2f(b4[3]) + x4.w;
        *(float4*)(ob + (size_t)c*N_ + n0 + 4*nq) = y;
    }
}

// ---------------------------------------------------------------------------
extern "C" void kernel_launch(void* const* d_in, const int* in_sizes, int n_in,
                              void* d_out, int out_size, void* d_ws, size_t ws_size,
                              hipStream_t stream) {
    const float* x     = (const float*)d_in[0];
    const float* Wq    = (const float*)d_in[1];
    const float* bq    = (const float*)d_in[2];
    const float* Wk    = (const float*)d_in[3];
    const float* bk    = (const float*)d_in[4];
    const float* Wv    = (const float*)d_in[5];
    const float* bv    = (const float*)d_in[6];
    const float* gamma = (const float*)d_in[7];
    float* out = (float*)d_out;

    // ws layout (~29.3 MB):
    unsigned short* Qg = (unsigned short*)d_ws;            // 2 MiB
    unsigned short* Kg = Qg + (size_t)B_*N_*D_;            // 2 MiB
    unsigned short* Vg = Kg + (size_t)B_*N_*D_;            // 8 MiB
    unsigned short* Op = Vg + (size_t)B_*C_*N_;            // 16.8 MiB
    float* ML = (float*)(Op + (size_t)2*B_*64*C_*64);      // 256 KiB
    unsigned short* WbfA = (unsigned short*)(ML + (size_t)2*B_*64*128); // 192 KiB

    convert_w<<<dim3(96), 256, 0, stream>>>(Wq, Wk, Wv, WbfA);
    proj_kernel<<<dim3(64, 3, 4), 256, 0, stream>>>(x, WbfA, bq, bk, bv,
                                                    Qg, Kg, Vg);
    flash_kernel<<<dim3(8, 64), 256, 0, stream>>>(Qg, Kg, Vg, Op, ML);
    combine_kernel<<<dim3(64, 2, 4), 256, 0, stream>>>(Op, ML, x, gamma, out);
}